// Round 8
// baseline (34.688 us; speedup 1.0000x reference)
//
#include <hip/hip_runtime.h>
#include <math.h>

#define HDIM 512
#define LDIM 256
#define NBLK 16   // 1 block/CU; each block: full gather + full t + 32 out rows

__device__ __forceinline__ void fma4(float4& a, float w, const float4& e) {
    a.x += w * e.x; a.y += w * e.y; a.z += w * e.z; a.w += w * e.w;
}
__device__ __forceinline__ float dot4(const float4& a, const float4& b) {
    return a.x * b.x + a.y * b.y + a.z * b.z + a.w * b.w;
}

// Single plain kernel, 16 blocks x 512 threads. No inter-block communication.
// A: blend weights + loc -> LDS.
// B: redundant gather-sum s (4 x 512): 4 groups x 64 rows, float4, 16-deep.
// C: LDS reduce of group partials.
// D: full t (t_up,t_lo in R^512): 8 waves x 64 rows; 16-lanes-per-row layout
//    (coalesced 256B/row reads), per-quad register accum, 4-level shfl_xor.
// E: 32 output rows per block (4 per wave), batched loads.
__global__ void __launch_bounds__(512)
strnn_single(const float* __restrict__ td_u, const float* __restrict__ td_l,
             const float* __restrict__ ld_u, const float* __restrict__ ld_l,
             const float* __restrict__ hx,   const float* __restrict__ W_ih,
             const float* __restrict__ W_thU, const float* __restrict__ W_thL,
             const float* __restrict__ W_shU, const float* __restrict__ W_shL,
             const float* __restrict__ table, const int* __restrict__ loc,
             float* __restrict__ out)
{
    __shared__ float4 w_s[LDIM];          // 4 KB
    __shared__ int    loc_s[LDIM];        // 1 KB
    __shared__ float  part[4][4 * HDIM];  // 32 KB
    __shared__ float  s_sm[4 * HDIM];     // 8 KB
    __shared__ float  t_up[HDIM];         // 2 KB
    __shared__ float  t_lo[HDIM];         // 2 KB
    const int tid  = threadIdx.x;
    const int wave = tid >> 6;
    const int lane = tid & 63;
    const int b    = blockIdx.x;

    // ---- A: per-l blend weights + indices ----
    if (tid < LDIM) {
        const int l = tid;
        const float a1 = td_u[l], b1 = td_l[l];
        const float beta = a1 / (a1 + b1);
        const float a2 = ld_u[l], b2 = ld_l[l];
        const float alpha = a2 / (a2 + b2);
        w_s[l] = make_float4(alpha * beta, alpha * (1.0f - beta),
                             (1.0f - alpha) * beta, (1.0f - alpha) * (1.0f - beta));
        loc_s[l] = loc[l];
    }
    __syncthreads();

    // ---- B: gather, group g of 4 sums rows [g*64, g*64+64) ----
    {
        const int g  = tid >> 7;
        const int c  = tid & 127;
        const int h4 = c * 4;
        const int lbase = g * 64;
        float4 a0 = {0,0,0,0}, a1v = {0,0,0,0}, a2v = {0,0,0,0}, a3v = {0,0,0,0};
        for (int base = 0; base < 64; base += 16) {
            float4 e[16];
#pragma unroll
            for (int k = 0; k < 16; ++k)
                e[k] = *(const float4*)(table + (size_t)loc_s[lbase + base + k] * HDIM + h4);
#pragma unroll
            for (int k = 0; k < 16; ++k) {
                const float4 w = w_s[lbase + base + k];
                fma4(a0,  w.x, e[k]);
                fma4(a1v, w.y, e[k]);
                fma4(a2v, w.z, e[k]);
                fma4(a3v, w.w, e[k]);
            }
        }
        *(float4*)(&part[g][0 * HDIM + h4]) = a0;
        *(float4*)(&part[g][1 * HDIM + h4]) = a1v;
        *(float4*)(&part[g][2 * HDIM + h4]) = a2v;
        *(float4*)(&part[g][3 * HDIM + h4]) = a3v;
    }
    __syncthreads();

    // ---- C: reduce 4 group-partials into s_sm ----
    {
        const int s0 = tid * 4;
        float4 r = {0,0,0,0};
#pragma unroll
        for (int p = 0; p < 4; ++p) {
            const float4 v = *(const float4*)(&part[p][s0]);
            r.x += v.x; r.y += v.y; r.z += v.z; r.w += v.w;
        }
        *(float4*)(&s_sm[s0]) = r;
    }
    __syncthreads();

    // ---- D: full t; wave owns 64 rows (16 quads of 4) ----
    {
        const int wbase = wave * 64;
        const int q16 = lane >> 4;   // row offset within quad (0..3)
        const int c   = lane & 15;   // col segment (0..15)
        float pu[16], pl[16];
#pragma unroll
        for (int q = 0; q < 16; ++q) { pu[q] = 0.f; pl[q] = 0.f; }

        for (int cb = 0; cb < 8; ++cb) {       // 8 col-blocks of 64
            const int col = cb * 64 + c * 4;
            const float4 s1 = *(const float4*)(s_sm + 0 * HDIM + col);
            const float4 s2 = *(const float4*)(s_sm + 1 * HDIM + col);
            const float4 s3 = *(const float4*)(s_sm + 2 * HDIM + col);
            const float4 s4 = *(const float4*)(s_sm + 3 * HDIM + col);
#pragma unroll
            for (int qq = 0; qq < 16; qq += 4) {
                float4 U[4], L4[4];
#pragma unroll
                for (int k = 0; k < 4; ++k) {
                    const size_t row = wbase + (qq + k) * 4 + q16;
                    U[k]  = *(const float4*)(W_thU + row * HDIM + col);
                    L4[k] = *(const float4*)(W_thL + row * HDIM + col);
                }
#pragma unroll
                for (int k = 0; k < 4; ++k) {
                    pu[qq + k] += dot4(U[k], s1) + dot4(L4[k], s2);
                    pl[qq + k] += dot4(U[k], s3) + dot4(L4[k], s4);
                }
            }
        }
        // reduce over the 16 col-segments (lane bits 0..3)
#pragma unroll
        for (int q = 0; q < 16; ++q) {
            float a = pu[q], d = pl[q];
#pragma unroll
            for (int off = 1; off < 16; off <<= 1) {
                a += __shfl_xor(a, off);
                d += __shfl_xor(d, off);
            }
            if (c == 0) {
                const int row = wbase + q * 4 + q16;
                t_up[row] = a;
                t_lo[row] = d;
            }
        }
    }
    __syncthreads();

    // ---- E: 32 out rows/block, 4 per wave, batched loads ----
    {
        const int r0 = b * 32 + wave * 4;
        float4 WU[4][2], WL[4][2], WI[4][2];
#pragma unroll
        for (int q = 0; q < 4; ++q) {
            const size_t row = (size_t)(r0 + q) * HDIM;
#pragma unroll
            for (int it = 0; it < 2; ++it) {
                const int j = it * 256 + lane * 4;
                WU[q][it] = *(const float4*)(W_shU + row + j);
                WL[q][it] = *(const float4*)(W_shL + row + j);
                WI[q][it] = *(const float4*)(W_ih + row + j);
            }
        }
        float4 TU[2], TL[2], HV[2];
#pragma unroll
        for (int it = 0; it < 2; ++it) {
            const int j = it * 256 + lane * 4;
            TU[it] = *(const float4*)(t_up + j);
            TL[it] = *(const float4*)(t_lo + j);
            HV[it] = *(const float4*)(hx + j);
        }
#pragma unroll
        for (int q = 0; q < 4; ++q) {
            float p = 0.f;
#pragma unroll
            for (int it = 0; it < 2; ++it) {
                p += dot4(WU[q][it], TU[it]) + dot4(WL[q][it], TL[it])
                   + dot4(WI[q][it], HV[it]);
            }
#pragma unroll
            for (int off = 32; off; off >>= 1) p += __shfl_down(p, off);
            if (lane == 0) out[r0 + q] = 1.0f / (1.0f + expf(-p));
        }
    }
}

extern "C" void kernel_launch(void* const* d_in, const int* in_sizes, int n_in,
                              void* d_out, int out_size, void* d_ws, size_t ws_size,
                              hipStream_t stream) {
    const float* td_u  = (const float*)d_in[0];
    const float* td_l  = (const float*)d_in[1];
    const float* ld_u  = (const float*)d_in[2];
    const float* ld_l  = (const float*)d_in[3];
    const float* hx    = (const float*)d_in[4];
    const float* W_ih  = (const float*)d_in[5];
    const float* W_thU = (const float*)d_in[6];
    const float* W_thL = (const float*)d_in[7];
    const float* W_shU = (const float*)d_in[8];
    const float* W_shL = (const float*)d_in[9];
    const float* table = (const float*)d_in[10];
    const int*   loc   = (const int*)d_in[11];

    float* out = (float*)d_out;

    strnn_single<<<NBLK, 512, 0, stream>>>(td_u, td_l, ld_u, ld_l, hx, W_ih,
                                           W_thU, W_thL, W_shU, W_shL,
                                           table, loc, out);
}

// Round 9
// 25.692 us; speedup vs baseline: 1.3501x; 1.3501x over previous
//
#include <hip/hip_runtime.h>
#include <math.h>

#define HDIM 512
#define LDIM 256
#define NB1 16      // node-1 blocks, each owns 32 columns
#define CSL 32      // column-slice width

__device__ __forceinline__ float dot4(const float4& a, const float4& b) {
    return a.x * b.x + a.y * b.y + a.z * b.z + a.w * b.w;
}

// Node 1: 16 blocks x 256 threads. Block b owns cols [32b, 32b+32).
// Gathers its col-slice of the 256 table rows, forms s-slice (4 x 32),
// computes partial t (up,lo in R^512 each) over its slice, writes the
// disjoint 4 KB chunk t_part[b]. Zero redundancy: table cols read once,
// W_th col-slices read once.
__global__ void __launch_bounds__(256)
k_part(const float* __restrict__ td_u, const float* __restrict__ td_l,
       const float* __restrict__ ld_u, const float* __restrict__ ld_l,
       const float* __restrict__ table, const int* __restrict__ loc,
       const float* __restrict__ W_thU, const float* __restrict__ W_thL,
       float* __restrict__ tpart /* [NB1][2*HDIM] */) {
    __shared__ float4 w_s[LDIM];         // blend weights per l
    __shared__ int    loc_s[LDIM];
    __shared__ float  g[LDIM][CSL];      // gathered col-slice (32 KB)
    __shared__ float  s_half[2][4][CSL];
    __shared__ float  s_sl[4][CSL];
    const int tid  = threadIdx.x;
    const int col0 = blockIdx.x * CSL;

    // blend weights + indices
    {
        const int l = tid;
        const float a1 = td_u[l], b1 = td_l[l];
        const float beta = a1 / (a1 + b1);
        const float a2 = ld_u[l], b2 = ld_l[l];
        const float alpha = a2 / (a2 + b2);
        w_s[l] = make_float4(alpha * beta, alpha * (1.0f - beta),
                             (1.0f - alpha) * beta, (1.0f - alpha) * (1.0f - beta));
        loc_s[l] = loc[l];
    }
    __syncthreads();

    // gather col-slice: 8 threads/row (8 x float4 = 128 B), 32 rows per sweep
    {
        const int r  = tid >> 3;       // row-group 0..31
        const int c8 = tid & 7;        // col segment
        for (int m = 0; m < 8; ++m) {
            const int l = m * 32 + r;
            const float4 v = *(const float4*)(table + (size_t)loc_s[l] * HDIM
                                              + col0 + c8 * 4);
            *(float4*)&g[l][c8 * 4] = v;
        }
    }
    __syncthreads();

    // s-slice: thread -> (j = tid&31, k = (tid>>5)&3, h = tid>>7); 128-term sum
    {
        const int j = tid & 31;
        const int k = (tid >> 5) & 3;
        const int h = tid >> 7;
        float acc = 0.f;
        const int l0 = h * 128;
#pragma unroll 8
        for (int l = l0; l < l0 + 128; ++l) {
            const float4 w = w_s[l];
            const float wk = (k == 0) ? w.x : (k == 1) ? w.y : (k == 2) ? w.z : w.w;
            acc += wk * g[l][j];
        }
        s_half[h][k][j] = acc;
    }
    __syncthreads();
    if (tid < 128) {
        const int j = tid & 31;
        const int k = tid >> 5;
        s_sl[k][j] = s_half[0][k][j] + s_half[1][k][j];
    }
    __syncthreads();

    // partial t: 8 lanes/row, 32 rows per sweep, 16 sweeps (512 rows)
    {
        const int r8 = tid >> 3;   // row-group 0..31
        const int c8 = tid & 7;    // col segment
        const float4 S1 = *(const float4*)&s_sl[0][c8 * 4];
        const float4 S2 = *(const float4*)&s_sl[1][c8 * 4];
        const float4 S3 = *(const float4*)&s_sl[2][c8 * 4];
        const float4 S4 = *(const float4*)&s_sl[3][c8 * 4];
        float* tp = tpart + (size_t)blockIdx.x * (2 * HDIM);
        for (int m = 0; m < 16; m += 4) {
            float4 U[4], L[4];
#pragma unroll
            for (int k = 0; k < 4; ++k) {
                const size_t row = (size_t)((m + k) * 32 + r8) * HDIM;
                U[k] = *(const float4*)(W_thU + row + col0 + c8 * 4);
                L[k] = *(const float4*)(W_thL + row + col0 + c8 * 4);
            }
#pragma unroll
            for (int k = 0; k < 4; ++k) {
                float pu = dot4(U[k], S1) + dot4(L[k], S2);
                float pl = dot4(U[k], S3) + dot4(L[k], S4);
                pu += __shfl_xor(pu, 1); pu += __shfl_xor(pu, 2); pu += __shfl_xor(pu, 4);
                pl += __shfl_xor(pl, 1); pl += __shfl_xor(pl, 2); pl += __shfl_xor(pl, 4);
                if (c8 == 0) {
                    const int i = (m + k) * 32 + r8;
                    tp[i] = pu;
                    tp[HDIM + i] = pl;
                }
            }
        }
    }
}

// Node 2: 128 blocks x 256 threads. Reduce 16 disjoint t-partials into LDS,
// then 4 output rows per block (1 per wave).
__global__ void __launch_bounds__(256)
k_out2(const float* __restrict__ WshU, const float* __restrict__ WshL,
       const float* __restrict__ Wih, const float* __restrict__ tpart,
       const float* __restrict__ hx, float* __restrict__ out) {
    __shared__ float t_comb[2 * HDIM];   // [t_up(512), t_lo(512)]
    const int tid  = threadIdx.x;
    const int wave = tid >> 6;
    const int lane = tid & 63;

    // reduce partials: thread owns float4 slot tid*4 of the 1024-vector
    {
        float4 r = {0, 0, 0, 0};
#pragma unroll 4
        for (int p = 0; p < NB1; ++p) {
            const float4 v = *(const float4*)(tpart + (size_t)p * (2 * HDIM) + tid * 4);
            r.x += v.x; r.y += v.y; r.z += v.z; r.w += v.w;
        }
        *(float4*)&t_comb[tid * 4] = r;
    }
    __syncthreads();

    const int i = blockIdx.x * 4 + wave;
    const float* wu = WshU + (size_t)i * HDIM;
    const float* wl = WshL + (size_t)i * HDIM;
    const float* wi = Wih + (size_t)i * HDIM;
    float p = 0.f;
#pragma unroll
    for (int it = 0; it < 2; ++it) {
        const int j = it * 256 + lane * 4;
        const float4 u   = *(const float4*)(wu + j);
        const float4 l4  = *(const float4*)(wl + j);
        const float4 wi4 = *(const float4*)(wi + j);
        const float4 tu  = *(const float4*)(t_comb + j);
        const float4 tl  = *(const float4*)(t_comb + HDIM + j);
        const float4 hv  = *(const float4*)(hx + j);
        p += dot4(u, tu) + dot4(l4, tl) + dot4(wi4, hv);
    }
#pragma unroll
    for (int off = 32; off; off >>= 1) p += __shfl_down(p, off);
    if (lane == 0) out[i] = 1.0f / (1.0f + expf(-p));
}

extern "C" void kernel_launch(void* const* d_in, const int* in_sizes, int n_in,
                              void* d_out, int out_size, void* d_ws, size_t ws_size,
                              hipStream_t stream) {
    const float* td_u  = (const float*)d_in[0];
    const float* td_l  = (const float*)d_in[1];
    const float* ld_u  = (const float*)d_in[2];
    const float* ld_l  = (const float*)d_in[3];
    const float* hx    = (const float*)d_in[4];
    const float* W_ih  = (const float*)d_in[5];
    const float* W_thU = (const float*)d_in[6];
    const float* W_thL = (const float*)d_in[7];
    const float* W_shU = (const float*)d_in[8];
    const float* W_shL = (const float*)d_in[9];
    const float* table = (const float*)d_in[10];
    const int*   loc   = (const int*)d_in[11];

    float* tpart = (float*)d_ws;   // NB1 * 2*HDIM floats, fully rewritten
    float* out   = (float*)d_out;

    k_part<<<NB1, 256, 0, stream>>>(td_u, td_l, ld_u, ld_l, table, loc,
                                    W_thU, W_thL, tpart);
    k_out2<<<HDIM / 4, 256, 0, stream>>>(W_shU, W_shL, W_ih, tpart, hx, out);
}

// Round 10
// 12.143 us; speedup vs baseline: 2.8566x; 2.1158x over previous
//
#include <hip/hip_runtime.h>
#include <math.h>

#define HDIM 512
#define LDIM 256
#define G 4     // l-groups (gather split)
#define P 32    // t-row chunks
// node-1 grid = G*P = 128 blocks; block b: g = b&3 (64 table rows), p = b>>2 (16 t-rows)

__device__ __forceinline__ void fma4(float4& a, float w, const float4& e) {
    a.x += w * e.x; a.y += w * e.y; a.z += w * e.z; a.w += w * e.w;
}
__device__ __forceinline__ float dot4(const float4& a, const float4& b) {
    return a.x * b.x + a.y * b.y + a.z * b.z + a.w * b.w;
}

// Node 1: 128 blocks x 256 threads. Block (g,p): partial-s over l-group g
// (64 rows, full-row coalesced gather), then 16 partial-t rows (chunk p)
// -> tpart[g][1024] (disjoint rows, no atomics, fully rewritten).
__global__ void __launch_bounds__(256)
k_part(const float* __restrict__ td_u, const float* __restrict__ td_l,
       const float* __restrict__ ld_u, const float* __restrict__ ld_l,
       const float* __restrict__ table, const int* __restrict__ loc,
       const float* __restrict__ W_thU, const float* __restrict__ W_thL,
       float* __restrict__ tpart /* [G][2*HDIM] */) {
    __shared__ float4 w_s[64];           // 1 KB
    __shared__ int    loc_s[64];
    __shared__ float  part[2][4 * HDIM]; // 16 KB
    __shared__ float  s_sm[4 * HDIM];    // 8 KB
    const int tid  = threadIdx.x;
    const int wave = tid >> 6;
    const int lane = tid & 63;
    const int g    = blockIdx.x & (G - 1);
    const int p    = blockIdx.x >> 2;
    const int lbase = g * 64;

    // ---- issue W_th row loads FIRST (independent of gather; hides latency) --
    const int r0 = p * 16 + wave * 4;    // this wave's 4 t-rows
    float4 WU[4][2], WL[4][2];
#pragma unroll
    for (int q = 0; q < 4; ++q) {
        const size_t row = (size_t)(r0 + q) * HDIM;
#pragma unroll
        for (int it = 0; it < 2; ++it) {
            const int j = it * 256 + lane * 4;
            WU[q][it] = *(const float4*)(W_thU + row + j);
            WL[q][it] = *(const float4*)(W_thL + row + j);
        }
    }

    // ---- blend weights + indices for this l-group ----
    if (tid < 64) {
        const int l = lbase + tid;
        const float a1 = td_u[l], b1 = td_l[l];
        const float beta = a1 / (a1 + b1);
        const float a2 = ld_u[l], b2 = ld_l[l];
        const float alpha = a2 / (a2 + b2);
        w_s[tid] = make_float4(alpha * beta, alpha * (1.0f - beta),
                               (1.0f - alpha) * beta, (1.0f - alpha) * (1.0f - beta));
        loc_s[tid] = loc[l];
    }
    __syncthreads();

    // ---- gather: half h (tid>>7) sums rows [h*32, h*32+32) of the group ----
    {
        const int h  = tid >> 7;
        const int c  = tid & 127;
        const int h4 = c * 4;
        const int rb = h * 32;
        float4 a0 = {0,0,0,0}, a1v = {0,0,0,0}, a2v = {0,0,0,0}, a3v = {0,0,0,0};
#pragma unroll
        for (int base = 0; base < 32; base += 16) {
            float4 e[16];
#pragma unroll
            for (int k = 0; k < 16; ++k)
                e[k] = *(const float4*)(table + (size_t)loc_s[rb + base + k] * HDIM + h4);
#pragma unroll
            for (int k = 0; k < 16; ++k) {
                const float4 w = w_s[rb + base + k];
                fma4(a0,  w.x, e[k]);
                fma4(a1v, w.y, e[k]);
                fma4(a2v, w.z, e[k]);
                fma4(a3v, w.w, e[k]);
            }
        }
        *(float4*)(&part[h][0 * HDIM + h4]) = a0;
        *(float4*)(&part[h][1 * HDIM + h4]) = a1v;
        *(float4*)(&part[h][2 * HDIM + h4]) = a2v;
        *(float4*)(&part[h][3 * HDIM + h4]) = a3v;
    }
    __syncthreads();

    // ---- reduce 2 halves into s_sm (thread owns 8 consecutive floats) ----
    {
        const int s0 = tid * 8;
        const float4 u0 = *(const float4*)(&part[0][s0]);
        const float4 u1 = *(const float4*)(&part[0][s0 + 4]);
        const float4 v0 = *(const float4*)(&part[1][s0]);
        const float4 v1 = *(const float4*)(&part[1][s0 + 4]);
        *(float4*)(&s_sm[s0])     = make_float4(u0.x + v0.x, u0.y + v0.y, u0.z + v0.z, u0.w + v0.w);
        *(float4*)(&s_sm[s0 + 4]) = make_float4(u1.x + v1.x, u1.y + v1.y, u1.z + v1.z, u1.w + v1.w);
    }
    __syncthreads();

    // ---- partial t: 4 rows per wave (R4 layout), write tpart[g] ----
    {
        float4 S1[2], S2[2], S3[2], S4[2];
#pragma unroll
        for (int it = 0; it < 2; ++it) {
            const int j = it * 256 + lane * 4;
            S1[it] = *(const float4*)(s_sm + 0 * HDIM + j);
            S2[it] = *(const float4*)(s_sm + 1 * HDIM + j);
            S3[it] = *(const float4*)(s_sm + 2 * HDIM + j);
            S4[it] = *(const float4*)(s_sm + 3 * HDIM + j);
        }
        float* tp = tpart + (size_t)g * (2 * HDIM);
#pragma unroll
        for (int q = 0; q < 4; ++q) {
            float pu = 0.f, pl = 0.f;
#pragma unroll
            for (int it = 0; it < 2; ++it) {
                pu += dot4(WU[q][it], S1[it]) + dot4(WL[q][it], S2[it]);
                pl += dot4(WU[q][it], S3[it]) + dot4(WL[q][it], S4[it]);
            }
#pragma unroll
            for (int off = 32; off; off >>= 1) {
                pu += __shfl_down(pu, off);
                pl += __shfl_down(pl, off);
            }
            if (lane == 0) { tp[r0 + q] = pu; tp[HDIM + r0 + q] = pl; }
        }
    }
}

// Node 2: 128 blocks x 256 threads. W loads issued first; reduce G=4
// t-partials (16 KB) into LDS; 4 output rows per block (1 per wave).
__global__ void __launch_bounds__(256)
k_out2(const float* __restrict__ WshU, const float* __restrict__ WshL,
       const float* __restrict__ Wih, const float* __restrict__ tpart,
       const float* __restrict__ hx, float* __restrict__ out) {
    __shared__ float t_comb[2 * HDIM];
    const int tid  = threadIdx.x;
    const int wave = tid >> 6;
    const int lane = tid & 63;
    const int i = blockIdx.x * 4 + wave;

    // issue independent loads first
    float4 WU[2], WL[2], WI[2], HV[2];
    {
        const size_t row = (size_t)i * HDIM;
#pragma unroll
        for (int it = 0; it < 2; ++it) {
            const int j = it * 256 + lane * 4;
            WU[it] = *(const float4*)(WshU + row + j);
            WL[it] = *(const float4*)(WshL + row + j);
            WI[it] = *(const float4*)(Wih + row + j);
            HV[it] = *(const float4*)(hx + j);
        }
    }

    // reduce 4 partials: thread owns float4 slot tid*4 of the 1024-vector
    {
        float4 r = {0, 0, 0, 0};
#pragma unroll
        for (int p = 0; p < G; ++p) {
            const float4 v = *(const float4*)(tpart + (size_t)p * (2 * HDIM) + tid * 4);
            r.x += v.x; r.y += v.y; r.z += v.z; r.w += v.w;
        }
        *(float4*)&t_comb[tid * 4] = r;
    }
    __syncthreads();

    float pacc = 0.f;
#pragma unroll
    for (int it = 0; it < 2; ++it) {
        const int j = it * 256 + lane * 4;
        const float4 tu = *(const float4*)(t_comb + j);
        const float4 tl = *(const float4*)(t_comb + HDIM + j);
        pacc += dot4(WU[it], tu) + dot4(WL[it], tl) + dot4(WI[it], HV[it]);
    }
#pragma unroll
    for (int off = 32; off; off >>= 1) pacc += __shfl_down(pacc, off);
    if (lane == 0) out[i] = 1.0f / (1.0f + expf(-pacc));
}

extern "C" void kernel_launch(void* const* d_in, const int* in_sizes, int n_in,
                              void* d_out, int out_size, void* d_ws, size_t ws_size,
                              hipStream_t stream) {
    const float* td_u  = (const float*)d_in[0];
    const float* td_l  = (const float*)d_in[1];
    const float* ld_u  = (const float*)d_in[2];
    const float* ld_l  = (const float*)d_in[3];
    const float* hx    = (const float*)d_in[4];
    const float* W_ih  = (const float*)d_in[5];
    const float* W_thU = (const float*)d_in[6];
    const float* W_thL = (const float*)d_in[7];
    const float* W_shU = (const float*)d_in[8];
    const float* W_shL = (const float*)d_in[9];
    const float* table = (const float*)d_in[10];
    const int*   loc   = (const int*)d_in[11];

    float* tpart = (float*)d_ws;   // G * 2*HDIM floats, fully rewritten each call
    float* out   = (float*)d_out;

    k_part<<<G * P, 256, 0, stream>>>(td_u, td_l, ld_u, ld_l, table, loc,
                                      W_thU, W_thL, tpart);
    k_out2<<<HDIM / 4, 256, 0, stream>>>(W_shU, W_shL, W_ih, tpart, hx, out);
}